// Round 4
// baseline (393.703 us; speedup 1.0000x reference)
//
#include <hip/hip_runtime.h>
#include <cstdint>
#include <cstddef>

#define NEG_SLOPE 0.2f

static __device__ __forceinline__ float leaky(float x){ return x > 0.f ? x : NEG_SLOPE*x; }
static __device__ __forceinline__ float pick4(float4 v, int h){
  float r = v.x;
  if (h==1) r = v.y;
  if (h==2) r = v.z;
  if (h==3) r = v.w;
  return r;
}
// order-preserving float <-> unsigned key (for atomicMax on floats)
static __device__ __forceinline__ unsigned fkey(float f){
  unsigned u = __float_as_uint(f);
  return (u & 0x80000000u) ? ~u : (u | 0x80000000u);
}
static __device__ __forceinline__ float fdecode(unsigned k){
  return __uint_as_float((k & 0x80000000u) ? (k ^ 0x80000000u) : ~k);
}

// ---------------- edge index dtype detection (sampled, single block) ----------------
__global__ __launch_bounds__(256) void k_detect(const unsigned int* __restrict__ w, int E,
                                                int* __restrict__ flag){
  __shared__ int s;
  if (threadIdx.x == 0) s = 0;
  __syncthreads();
  int nz = 0;
  long long total = 2LL * E;
  #pragma unroll
  for (int j = 0; j < 8; ++j){
    long long idx = ((long long)(threadIdx.x * 8 + j) * total) / 2048;
    idx |= 1;
    if (idx < total) nz |= (w[idx] != 0u);
  }
  if (__any(nz) && (threadIdx.x & 63) == 0) atomicOr(&s, 1);
  __syncthreads();
  if (threadIdx.x == 0) *flag = s;     // 1 => int32, 0 => int64
}

// ---------------- decode + histogram fused ----------------
__global__ __launch_bounds__(256) void k_decode_hist(const void* __restrict__ ei, int E,
                                                     const int* __restrict__ flag,
                                                     int* __restrict__ src, int* __restrict__ dst,
                                                     int* __restrict__ cnt){
  int i = blockIdx.x*256 + threadIdx.x;
  if (i >= E) return;
  int s, d;
  if (*flag){ // int32
    const int* p = (const int*)ei;
    s = p[i]; d = p[E+i];
  } else {    // int64
    const long long* p = (const long long*)ei;
    s = (int)p[i]; d = (int)p[E+i];
  }
  src[i] = s; dst[i] = d;
  atomicAdd(&cnt[d], 1);
}

// ---------------- CSR build by destination ----------------
__global__ __launch_bounds__(256) void k_scan1(const int* __restrict__ cnt, int* __restrict__ rowptr,
                                               int* __restrict__ bsum, int N){
  __shared__ int s[256];
  int tid = threadIdx.x;
  int base = blockIdx.x*1024 + tid*4;
  int v0=0,v1=0,v2=0,v3=0;
  if (base+0 < N) v0 = cnt[base+0];
  if (base+1 < N) v1 = cnt[base+1];
  if (base+2 < N) v2 = cnt[base+2];
  if (base+3 < N) v3 = cnt[base+3];
  s[tid] = v0+v1+v2+v3;
  __syncthreads();
  for (int offd=1; offd<256; offd<<=1){
    int t = (tid>=offd) ? s[tid-offd] : 0;
    __syncthreads();
    s[tid] += t;
    __syncthreads();
  }
  int run = (tid>0) ? s[tid-1] : 0;
  run += v0; if (base+0 < N) rowptr[base+1] = run;
  run += v1; if (base+1 < N) rowptr[base+2] = run;
  run += v2; if (base+2 < N) rowptr[base+3] = run;
  run += v3; if (base+3 < N) rowptr[base+4] = run;
  if (tid==255) bsum[blockIdx.x] = s[255];
}

__global__ void k_scan2(int* __restrict__ bsum, int nb){
  if (threadIdx.x==0 && blockIdx.x==0){
    int acc=0;
    for (int i=0;i<nb;i++){ int t=bsum[i]; bsum[i]=acc; acc+=t; }
  }
}

__global__ __launch_bounds__(256) void k_scan3(int* __restrict__ rowptr, const int* __restrict__ bsum,
                                               int N){
  int tid = threadIdx.x;
  int base = blockIdx.x*1024 + tid*4;
  int add = bsum[blockIdx.x];
  #pragma unroll
  for (int j=0;j<4;j++){ int idx = base+j; if (idx < N) rowptr[idx+1] += add; }
  if (blockIdx.x==0 && tid==0) rowptr[0] = 0;
}

__global__ __launch_bounds__(256) void k_scatter(const int* __restrict__ src, const int* __restrict__ dst,
                                                 int E, const int* __restrict__ rowptr,
                                                 int* __restrict__ fill, int* __restrict__ csr_src){
  int i = blockIdx.x*256 + threadIdx.x;
  if (i >= E) return;
  int d = dst[i];
  int pos = rowptr[d] + atomicAdd(&fill[d], 1);
  csr_src[pos] = src[i];
}

// ---------------- fp32 tiled GEMM: C[M,256] = A[M,256] @ B[256,256] ----------------
#define GBM 128
#define GBN 128
#define GBK 16
__global__ __launch_bounds__(256) void k_gemm1(const float* __restrict__ A, const float* __restrict__ B,
                                               float* __restrict__ C, int M){
  __shared__ float As[GBK][GBM+4];   // transposed: As[k][m]
  __shared__ float Bs[GBK][GBN];
  const int K = 256, NC = 256;
  int bm = blockIdx.x * GBM;
  int bn = blockIdx.y * GBN;
  int tid = threadIdx.x;
  int tm = tid >> 4;    // 0..15, owns 8 rows
  int tn = tid & 15;    // 0..15, owns 8 cols
  float acc[8][8];
  #pragma unroll
  for (int i=0;i<8;i++)
    #pragma unroll
    for (int j=0;j<8;j++) acc[i][j] = 0.f;

  for (int k0 = 0; k0 < K; k0 += GBK){
    // A tile: 128 rows x 16 k = 512 float4, 2 per thread
    #pragma unroll
    for (int f = tid; f < 512; f += 256){
      int row = f >> 2;
      int kk  = (f & 3) << 2;
      int gr  = bm + row;
      float4 v = make_float4(0.f,0.f,0.f,0.f);
      if (gr < M) v = *(const float4*)&A[(size_t)gr*K + k0 + kk];
      As[kk+0][row] = v.x; As[kk+1][row] = v.y; As[kk+2][row] = v.z; As[kk+3][row] = v.w;
    }
    // B tile: 16 k x 128 cols = 512 float4, 2 per thread
    #pragma unroll
    for (int f = tid; f < 512; f += 256){
      int row = f >> 5;          // 0..15
      int col = (f & 31) << 2;   // 0..124
      *(float4*)&Bs[row][col] = *(const float4*)&B[(size_t)(k0+row)*NC + bn + col];
    }
    __syncthreads();
    #pragma unroll
    for (int kk = 0; kk < GBK; ++kk){
      float a[8], b[8];
      *(float4*)&a[0] = *(const float4*)&As[kk][tm*8];
      *(float4*)&a[4] = *(const float4*)&As[kk][tm*8+4];
      *(float4*)&b[0] = *(const float4*)&Bs[kk][tn*8];
      *(float4*)&b[4] = *(const float4*)&Bs[kk][tn*8+4];
      #pragma unroll
      for (int i=0;i<8;i++)
        #pragma unroll
        for (int j=0;j<8;j++)
          acc[i][j] = fmaf(a[i], b[j], acc[i][j]);
    }
    __syncthreads();
  }
  #pragma unroll
  for (int i=0;i<8;i++){
    int gr = bm + tm*8 + i;
    if (gr < M){
      *(float4*)&C[(size_t)gr*NC + bn + tn*8]     = make_float4(acc[i][0],acc[i][1],acc[i][2],acc[i][3]);
      *(float4*)&C[(size_t)gr*NC + bn + tn*8 + 4] = make_float4(acc[i][4],acc[i][5],acc[i][6],acc[i][7]);
    }
  }
}

// ---------------- per-node attention dot products: alpha_s/alpha_d [N][4] ----------------
__global__ __launch_bounds__(256) void k_alphas(const float* __restrict__ xw,
                                                const float* __restrict__ a_src, const float* __restrict__ a_dst,
                                                float* __restrict__ as1, float* __restrict__ ad1, int N){
  int wave = threadIdx.x >> 6, lane = threadIdx.x & 63;
  int n = blockIdx.x*4 + wave;
  if (n >= N) return;
  float4 v  = *(const float4*)&xw[(size_t)n*256 + lane*4];
  float4 sa = *(const float4*)&a_src[lane*4];
  float4 da = *(const float4*)&a_dst[lane*4];
  float ds = v.x*sa.x + v.y*sa.y + v.z*sa.z + v.w*sa.w;
  float dd = v.x*da.x + v.y*da.y + v.z*da.z + v.w*da.w;
  ds += __shfl_xor(ds, 1);  dd += __shfl_xor(dd, 1);
  ds += __shfl_xor(ds, 2);  dd += __shfl_xor(dd, 2);
  ds += __shfl_xor(ds, 4);  dd += __shfl_xor(dd, 4);
  ds += __shfl_xor(ds, 8);  dd += __shfl_xor(dd, 8);
  if ((lane & 15) == 0){
    int h = lane >> 4;
    as1[n*4 + h] = ds;
    ad1[n*4 + h] = dd;
  }
}

// ---------------- global per-head max of as1 (softmax-stabilization constant) ----------------
__global__ __launch_bounds__(256) void k_maxas(const float* __restrict__ as1, unsigned* __restrict__ gkey,
                                               int N){
  int lane = threadIdx.x & 63;
  float4 m = make_float4(-1e30f,-1e30f,-1e30f,-1e30f);
  for (int n = blockIdx.x*256 + threadIdx.x; n < N; n += gridDim.x*256){
    float4 v = *(const float4*)&as1[(size_t)n*4];
    m.x = fmaxf(m.x, v.x); m.y = fmaxf(m.y, v.y);
    m.z = fmaxf(m.z, v.z); m.w = fmaxf(m.w, v.w);
  }
  #pragma unroll
  for (int off = 1; off < 64; off <<= 1){
    m.x = fmaxf(m.x, __shfl_xor(m.x, off));
    m.y = fmaxf(m.y, __shfl_xor(m.y, off));
    m.z = fmaxf(m.z, __shfl_xor(m.z, off));
    m.w = fmaxf(m.w, __shfl_xor(m.w, off));
  }
  if (lane == 0){
    atomicMax(&gkey[0], fkey(m.x));
    atomicMax(&gkey[1], fkey(m.y));
    atomicMax(&gkey[2], fkey(m.z));
    atomicMax(&gkey[3], fkey(m.w));
  }
}

// ---------------- layer-1 aggregation: single pass, one wave per destination node ----------------
__global__ __launch_bounds__(256) void k_agg1(const int* __restrict__ rowptr, const int* __restrict__ csr_src,
                                              const float* __restrict__ as1, const float* __restrict__ ad1,
                                              const unsigned* __restrict__ gkey,
                                              const float* __restrict__ xw, const float* __restrict__ b1,
                                              float* __restrict__ hout, int N){
  int wave = threadIdx.x >> 6, lane = threadIdx.x & 63;
  int n = blockIdx.x*4 + wave;
  if (n >= N) return;
  int hd = lane >> 4;                       // head of this lane's 4 features
  float ad_h  = pick4(*(const float4*)&ad1[n*4], hd);
  float as_n  = pick4(*(const float4*)&as1[n*4], hd);
  // M >= every e in this (dst,head) segment: alpha invariant to the constant
  float Mh = leaky(fdecode(gkey[hd]) + ad_h);
  float p = __expf(leaky(as_n + ad_h) - Mh);   // self loop
  float denom = p;
  float4 v = *(const float4*)&xw[(size_t)n*256 + lane*4];
  float4 acc; acc.x = p*v.x; acc.y = p*v.y; acc.z = p*v.z; acc.w = p*v.w;
  int r0 = __builtin_amdgcn_readfirstlane(rowptr[n]);
  int r1 = __builtin_amdgcn_readfirstlane(rowptr[n+1]);
  int i = r0;
  for (; i + 2 <= r1; i += 2){
    int s0 = csr_src[i], s1 = csr_src[i+1];
    float4 a0 = *(const float4*)&as1[(size_t)s0*4];
    float4 a1 = *(const float4*)&as1[(size_t)s1*4];
    float4 w0 = *(const float4*)&xw[(size_t)s0*256 + lane*4];
    float4 w1 = *(const float4*)&xw[(size_t)s1*256 + lane*4];
    float p0 = __expf(leaky(pick4(a0,hd) + ad_h) - Mh);
    float p1 = __expf(leaky(pick4(a1,hd) + ad_h) - Mh);
    denom += p0 + p1;
    acc.x = fmaf(p1, w1.x, fmaf(p0, w0.x, acc.x));
    acc.y = fmaf(p1, w1.y, fmaf(p0, w0.y, acc.y));
    acc.z = fmaf(p1, w1.z, fmaf(p0, w0.z, acc.z));
    acc.w = fmaf(p1, w1.w, fmaf(p0, w0.w, acc.w));
  }
  if (i < r1){
    int s = csr_src[i];
    float4 a = *(const float4*)&as1[(size_t)s*4];
    float4 w = *(const float4*)&xw[(size_t)s*256 + lane*4];
    float pe = __expf(leaky(pick4(a,hd) + ad_h) - Mh);
    denom += pe;
    acc.x = fmaf(pe, w.x, acc.x);
    acc.y = fmaf(pe, w.y, acc.y);
    acc.z = fmaf(pe, w.z, acc.z);
    acc.w = fmaf(pe, w.w, acc.w);
  }
  float inv = 1.0f / (denom + 1e-16f);
  float4 bv = *(const float4*)&b1[lane*4];
  float4 o;
  o.x = fmaxf(fmaf(acc.x, inv, bv.x), 0.f);
  o.y = fmaxf(fmaf(acc.y, inv, bv.y), 0.f);
  o.z = fmaxf(fmaf(acc.z, inv, bv.z), 0.f);
  o.w = fmaxf(fmaf(acc.w, inv, bv.w), 0.f);
  *(float4*)&hout[(size_t)n*256 + lane*4] = o;
}

// ---------------- layer-2 projection: z[n] = dot(h[n], w2) ----------------
__global__ __launch_bounds__(256) void k_gemv(const float* __restrict__ h, const float* __restrict__ w2,
                                              float* __restrict__ z, int N){
  int wave = threadIdx.x >> 6, lane = threadIdx.x & 63;
  int n = blockIdx.x*4 + wave;
  if (n >= N) return;
  float4 v = *(const float4*)&h[(size_t)n*256 + lane*4];
  float4 w = *(const float4*)&w2[lane*4];
  float d = v.x*w.x + v.y*w.y + v.z*w.z + v.w*w.w;
  d += __shfl_xor(d, 1);
  d += __shfl_xor(d, 2);
  d += __shfl_xor(d, 4);
  d += __shfl_xor(d, 8);
  d += __shfl_xor(d, 16);
  d += __shfl_xor(d, 32);
  if (lane == 0) z[n] = d;
}

// ---------------- layer-2 aggregation (H=F=1): one wave per node, lanes over edges ----------------
__global__ __launch_bounds__(256) void k_agg2(const int* __restrict__ rowptr, const int* __restrict__ csr_src,
                                              const float* __restrict__ z,
                                              const float* __restrict__ as2p, const float* __restrict__ ad2p,
                                              const float* __restrict__ b2p,
                                              float* __restrict__ out, int N){
  int wave = threadIdx.x >> 6, lane = threadIdx.x & 63;
  int n = blockIdx.x*4 + wave;
  if (n >= N) return;
  float cas = as2p[0], cad = ad2p[0], cb = b2p[0];
  float zn = z[n];
  float adn = cad * zn;
  float e_self = leaky(cas*zn + adn);
  int r0 = __builtin_amdgcn_readfirstlane(rowptr[n]);
  int r1 = __builtin_amdgcn_readfirstlane(rowptr[n+1]);
  float m = e_self;
  for (int i = r0 + lane; i < r1; i += 64){
    int s = csr_src[i];
    m = fmaxf(m, leaky(cas*z[s] + adn));
  }
  m = fmaxf(m, __shfl_xor(m, 1));
  m = fmaxf(m, __shfl_xor(m, 2));
  m = fmaxf(m, __shfl_xor(m, 4));
  m = fmaxf(m, __shfl_xor(m, 8));
  m = fmaxf(m, __shfl_xor(m, 16));
  m = fmaxf(m, __shfl_xor(m, 32));
  float num = 0.f, den = 0.f;
  if (lane == 0){
    float p = __expf(e_self - m);
    den = p; num = p * zn;
  }
  for (int i = r0 + lane; i < r1; i += 64){
    int s = csr_src[i];
    float zs = z[s];
    float e = leaky(cas*zs + adn);
    float p = __expf(e - m);
    den += p;
    num = fmaf(p, zs, num);
  }
  num += __shfl_xor(num, 1);  den += __shfl_xor(den, 1);
  num += __shfl_xor(num, 2);  den += __shfl_xor(den, 2);
  num += __shfl_xor(num, 4);  den += __shfl_xor(den, 4);
  num += __shfl_xor(num, 8);  den += __shfl_xor(den, 8);
  num += __shfl_xor(num, 16); den += __shfl_xor(den, 16);
  num += __shfl_xor(num, 32); den += __shfl_xor(den, 32);
  if (lane == 0) out[n] = num / (den + 1e-16f) + cb;
}

// ---------------- launch ----------------
extern "C" void kernel_launch(void* const* d_in, const int* in_sizes, int n_in,
                              void* d_out, int out_size, void* d_ws, size_t ws_size,
                              hipStream_t stream){
  const float* x    = (const float*)d_in[0];
  const void*  ei   = d_in[1];
  const float* w1   = (const float*)d_in[2];
  const float* asw1 = (const float*)d_in[3];
  const float* adw1 = (const float*)d_in[4];
  const float* b1   = (const float*)d_in[5];
  const float* w2   = (const float*)d_in[6];
  const float* as2  = (const float*)d_in[7];
  const float* ad2  = (const float*)d_in[8];
  const float* b2   = (const float*)d_in[9];
  const int N = in_sizes[0] / 256;
  const int E = in_sizes[1] / 2;
  float* out = (float*)d_out;

  char* wsb = (char*)d_ws;
  size_t off = 0;
  auto alloc = [&](size_t bytes) -> void* {
    void* p = wsb + off;
    off = (off + bytes + 255) & ~(size_t)255;
    return p;
  };
  int*      flag    = (int*)     alloc(4);
  unsigned* gkey    = (unsigned*)alloc(16);
  int*      src     = (int*)     alloc((size_t)E*4);
  int*      dst     = (int*)     alloc((size_t)E*4);
  int*      cnt     = (int*)     alloc((size_t)N*4);
  int*      fill    = (int*)     alloc((size_t)N*4);
  int*      rowptr  = (int*)     alloc((size_t)(N+1)*4);
  int*      bsum    = (int*)     alloc(1024*4);
  int*      csr_src = (int*)     alloc((size_t)E*4);
  float*    xw      = (float*)   alloc((size_t)N*256*4);
  float*    as1     = (float*)   alloc((size_t)N*4*4);
  float*    ad1     = (float*)   alloc((size_t)N*4*4);
  float*    hbuf    = (float*)   alloc((size_t)N*256*4);
  float*    z       = (float*)   alloc((size_t)N*4);

  hipMemsetAsync(gkey, 0, 16, stream);
  hipMemsetAsync(cnt,  0, (size_t)N*4, stream);
  hipMemsetAsync(fill, 0, (size_t)N*4, stream);

  int gE = (E + 255) / 256;
  k_detect     <<<1, 256, 0, stream>>>((const unsigned int*)ei, E, flag);
  k_decode_hist<<<gE, 256, 0, stream>>>(ei, E, flag, src, dst, cnt);
  int nb = (N + 1023) / 1024;
  k_scan1  <<<nb, 256, 0, stream>>>(cnt, rowptr, bsum, N);
  k_scan2  <<<1, 64, 0, stream>>>(bsum, nb);
  k_scan3  <<<nb, 256, 0, stream>>>(rowptr, bsum, N);
  k_scatter<<<gE, 256, 0, stream>>>(src, dst, E, rowptr, fill, csr_src);

  dim3 gG((N + GBM - 1) / GBM, 256 / GBN);
  k_gemm1  <<<gG, 256, 0, stream>>>(x, w1, xw, N);

  int gN4 = (N + 3) / 4;
  k_alphas <<<gN4, 256, 0, stream>>>(xw, asw1, adw1, as1, ad1, N);
  k_maxas  <<<64, 256, 0, stream>>>(as1, gkey, N);
  k_agg1   <<<gN4, 256, 0, stream>>>(rowptr, csr_src, as1, ad1, gkey, xw, b1, hbuf, N);
  k_gemv   <<<gN4, 256, 0, stream>>>(hbuf, w2, z, N);
  k_agg2   <<<gN4, 256, 0, stream>>>(rowptr, csr_src, z, as2, ad2, b2, out, N);
}

// Round 5
// 380.388 us; speedup vs baseline: 1.0350x; 1.0350x over previous
//
#include <hip/hip_runtime.h>
#include <cstdint>
#include <cstddef>

#define NEG_SLOPE 0.2f

static __device__ __forceinline__ float leaky(float x){ return x > 0.f ? x : NEG_SLOPE*x; }
// order-preserving float <-> unsigned key (for atomicMax on floats)
static __device__ __forceinline__ unsigned fkey(float f){
  unsigned u = __float_as_uint(f);
  return (u & 0x80000000u) ? ~u : (u | 0x80000000u);
}
static __device__ __forceinline__ float fdecode(unsigned k){
  return __uint_as_float((k & 0x80000000u) ? (k ^ 0x80000000u) : ~k);
}

// ---------------- edge index dtype detection (sampled, single block) ----------------
__global__ __launch_bounds__(256) void k_detect(const unsigned int* __restrict__ w, int E,
                                                int* __restrict__ flag){
  __shared__ int s;
  if (threadIdx.x == 0) s = 0;
  __syncthreads();
  int nz = 0;
  long long total = 2LL * E;
  #pragma unroll
  for (int j = 0; j < 8; ++j){
    long long idx = ((long long)(threadIdx.x * 8 + j) * total) / 2048;
    idx |= 1;
    if (idx < total) nz |= (w[idx] != 0u);
  }
  if (__any(nz) && (threadIdx.x & 63) == 0) atomicOr(&s, 1);
  __syncthreads();
  if (threadIdx.x == 0) *flag = s;     // 1 => int32, 0 => int64
}

// ---------------- decode + histogram fused ----------------
__global__ __launch_bounds__(256) void k_decode_hist(const void* __restrict__ ei, int E,
                                                     const int* __restrict__ flag,
                                                     int* __restrict__ src, int* __restrict__ dst,
                                                     int* __restrict__ cnt){
  int i = blockIdx.x*256 + threadIdx.x;
  if (i >= E) return;
  int s, d;
  if (*flag){ // int32
    const int* p = (const int*)ei;
    s = p[i]; d = p[E+i];
  } else {    // int64
    const long long* p = (const long long*)ei;
    s = (int)p[i]; d = (int)p[E+i];
  }
  src[i] = s; dst[i] = d;
  atomicAdd(&cnt[d], 1);
}

// ---------------- CSR build by destination ----------------
__global__ __launch_bounds__(256) void k_scan1(const int* __restrict__ cnt, int* __restrict__ rowptr,
                                               int* __restrict__ bsum, int N){
  __shared__ int s[256];
  int tid = threadIdx.x;
  int base = blockIdx.x*1024 + tid*4;
  int v0=0,v1=0,v2=0,v3=0;
  if (base+0 < N) v0 = cnt[base+0];
  if (base+1 < N) v1 = cnt[base+1];
  if (base+2 < N) v2 = cnt[base+2];
  if (base+3 < N) v3 = cnt[base+3];
  s[tid] = v0+v1+v2+v3;
  __syncthreads();
  for (int offd=1; offd<256; offd<<=1){
    int t = (tid>=offd) ? s[tid-offd] : 0;
    __syncthreads();
    s[tid] += t;
    __syncthreads();
  }
  int run = (tid>0) ? s[tid-1] : 0;
  run += v0; if (base+0 < N) rowptr[base+1] = run;
  run += v1; if (base+1 < N) rowptr[base+2] = run;
  run += v2; if (base+2 < N) rowptr[base+3] = run;
  run += v3; if (base+3 < N) rowptr[base+4] = run;
  if (tid==255) bsum[blockIdx.x] = s[255];
}

__global__ void k_scan2(int* __restrict__ bsum, int nb){
  if (threadIdx.x==0 && blockIdx.x==0){
    int acc=0;
    for (int i=0;i<nb;i++){ int t=bsum[i]; bsum[i]=acc; acc+=t; }
  }
}

__global__ __launch_bounds__(256) void k_scan3(int* __restrict__ rowptr, const int* __restrict__ bsum,
                                               int N){
  int tid = threadIdx.x;
  int base = blockIdx.x*1024 + tid*4;
  int add = bsum[blockIdx.x];
  #pragma unroll
  for (int j=0;j<4;j++){ int idx = base+j; if (idx < N) rowptr[idx+1] += add; }
  if (blockIdx.x==0 && tid==0) rowptr[0] = 0;
}

__global__ __launch_bounds__(256) void k_scatter(const int* __restrict__ src, const int* __restrict__ dst,
                                                 int E, const int* __restrict__ rowptr,
                                                 int* __restrict__ fill, int* __restrict__ csr_src){
  int i = blockIdx.x*256 + threadIdx.x;
  if (i >= E) return;
  int d = dst[i];
  int pos = rowptr[d] + atomicAdd(&fill[d], 1);
  csr_src[pos] = src[i];
}

// ---------------- fp32 tiled GEMM: C[M,256] = A[M,256] @ B[256,256] ----------------
#define GBM 128
#define GBN 128
#define GBK 32
__global__ __launch_bounds__(256) void k_gemm1(const float* __restrict__ A, const float* __restrict__ B,
                                               float* __restrict__ C, int M){
  __shared__ float As[GBK][GBM+4];   // transposed: As[k][m]
  __shared__ float Bs[GBK][GBN];
  const int K = 256, NC = 256;
  int bm = blockIdx.x * GBM;
  int bn = blockIdx.y * GBN;
  int tid = threadIdx.x;
  int tm = tid >> 4;    // 0..15, owns 8 rows
  int tn = tid & 15;    // 0..15, owns 8 cols
  float acc[8][8];
  #pragma unroll
  for (int i=0;i<8;i++)
    #pragma unroll
    for (int j=0;j<8;j++) acc[i][j] = 0.f;

  for (int k0 = 0; k0 < K; k0 += GBK){
    // A tile: 128 rows x 32 k = 1024 float4, 4 per thread
    #pragma unroll
    for (int f = tid; f < 1024; f += 256){
      int row = f >> 3;          // 0..127
      int kk  = (f & 7) << 2;    // 0..28
      int gr  = bm + row;
      float4 v = make_float4(0.f,0.f,0.f,0.f);
      if (gr < M) v = *(const float4*)&A[(size_t)gr*K + k0 + kk];
      As[kk+0][row] = v.x; As[kk+1][row] = v.y; As[kk+2][row] = v.z; As[kk+3][row] = v.w;
    }
    // B tile: 32 k x 128 cols = 1024 float4, 4 per thread
    #pragma unroll
    for (int f = tid; f < 1024; f += 256){
      int row = f >> 5;          // 0..31
      int col = (f & 31) << 2;   // 0..124
      *(float4*)&Bs[row][col] = *(const float4*)&B[(size_t)(k0+row)*NC + bn + col];
    }
    __syncthreads();
    #pragma unroll
    for (int kk = 0; kk < GBK; ++kk){
      float a[8], b[8];
      *(float4*)&a[0] = *(const float4*)&As[kk][tm*8];
      *(float4*)&a[4] = *(const float4*)&As[kk][tm*8+4];
      *(float4*)&b[0] = *(const float4*)&Bs[kk][tn*8];
      *(float4*)&b[4] = *(const float4*)&Bs[kk][tn*8+4];
      #pragma unroll
      for (int i=0;i<8;i++)
        #pragma unroll
        for (int j=0;j<8;j++)
          acc[i][j] = fmaf(a[i], b[j], acc[i][j]);
    }
    __syncthreads();
  }
  #pragma unroll
  for (int i=0;i<8;i++){
    int gr = bm + tm*8 + i;
    if (gr < M){
      *(float4*)&C[(size_t)gr*NC + bn + tn*8]     = make_float4(acc[i][0],acc[i][1],acc[i][2],acc[i][3]);
      *(float4*)&C[(size_t)gr*NC + bn + tn*8 + 4] = make_float4(acc[i][4],acc[i][5],acc[i][6],acc[i][7]);
    }
  }
}

// ---------------- per-node attention dot products: alpha_s/alpha_d [N][4] ----------------
__global__ __launch_bounds__(256) void k_alphas(const float* __restrict__ xw,
                                                const float* __restrict__ a_src, const float* __restrict__ a_dst,
                                                float* __restrict__ as1, float* __restrict__ ad1, int N){
  int wave = threadIdx.x >> 6, lane = threadIdx.x & 63;
  int n = blockIdx.x*4 + wave;
  if (n >= N) return;
  float4 v  = *(const float4*)&xw[(size_t)n*256 + lane*4];
  float4 sa = *(const float4*)&a_src[lane*4];
  float4 da = *(const float4*)&a_dst[lane*4];
  float ds = v.x*sa.x + v.y*sa.y + v.z*sa.z + v.w*sa.w;
  float dd = v.x*da.x + v.y*da.y + v.z*da.z + v.w*da.w;
  ds += __shfl_xor(ds, 1);  dd += __shfl_xor(dd, 1);
  ds += __shfl_xor(ds, 2);  dd += __shfl_xor(dd, 2);
  ds += __shfl_xor(ds, 4);  dd += __shfl_xor(dd, 4);
  ds += __shfl_xor(ds, 8);  dd += __shfl_xor(dd, 8);
  if ((lane & 15) == 0){
    int h = lane >> 4;
    as1[n*4 + h] = ds;
    ad1[n*4 + h] = dd;
  }
}

// ---------------- global per-head max of as1 (softmax-stabilization constant) ----------------
__global__ __launch_bounds__(256) void k_maxas(const float* __restrict__ as1, unsigned* __restrict__ gkey,
                                               int N){
  int lane = threadIdx.x & 63;
  float4 m = make_float4(-1e30f,-1e30f,-1e30f,-1e30f);
  for (int n = blockIdx.x*256 + threadIdx.x; n < N; n += gridDim.x*256){
    float4 v = *(const float4*)&as1[(size_t)n*4];
    m.x = fmaxf(m.x, v.x); m.y = fmaxf(m.y, v.y);
    m.z = fmaxf(m.z, v.z); m.w = fmaxf(m.w, v.w);
  }
  #pragma unroll
  for (int off = 1; off < 64; off <<= 1){
    m.x = fmaxf(m.x, __shfl_xor(m.x, off));
    m.y = fmaxf(m.y, __shfl_xor(m.y, off));
    m.z = fmaxf(m.z, __shfl_xor(m.z, off));
    m.w = fmaxf(m.w, __shfl_xor(m.w, off));
  }
  if (lane == 0){
    atomicMax(&gkey[0], fkey(m.x));
    atomicMax(&gkey[1], fkey(m.y));
    atomicMax(&gkey[2], fkey(m.z));
    atomicMax(&gkey[3], fkey(m.w));
  }
}

// ---------------- layer-1 aggregation + fused layer-2 projection ----------------
// h[n] is only ever consumed as z[n] = dot(h[n], w2) -> never materialize h.
__global__ __launch_bounds__(256) void k_agg1(const int* __restrict__ rowptr, const int* __restrict__ csr_src,
                                              const float* __restrict__ as1, const float* __restrict__ ad1,
                                              const unsigned* __restrict__ gkey,
                                              const float* __restrict__ xw, const float* __restrict__ b1,
                                              const float* __restrict__ w2,
                                              float* __restrict__ z, int N){
  int wave = threadIdx.x >> 6, lane = threadIdx.x & 63;
  int n = blockIdx.x*4 + wave;
  if (n >= N) return;
  int hd = lane >> 4;                       // head of this lane's 4 features
  float ad_h  = ad1[n*4 + hd];
  float as_n  = as1[n*4 + hd];
  // M >= every e in this (dst,head) segment: alpha invariant to the constant
  float Mh = leaky(fdecode(gkey[hd]) + ad_h);
  float p = __expf(leaky(as_n + ad_h) - Mh);   // self loop
  float denom = p;
  float4 v = *(const float4*)&xw[(size_t)n*256 + lane*4];
  float4 acc; acc.x = p*v.x; acc.y = p*v.y; acc.z = p*v.z; acc.w = p*v.w;
  int r0 = __builtin_amdgcn_readfirstlane(rowptr[n]);
  int r1 = __builtin_amdgcn_readfirstlane(rowptr[n+1]);
  int i = r0;
  // unroll x4: keep 4 independent 1KB gathers in flight per wave
  for (; i + 4 <= r1; i += 4){
    int s0 = csr_src[i], s1 = csr_src[i+1], s2 = csr_src[i+2], s3 = csr_src[i+3];
    float4 w0 = *(const float4*)&xw[(size_t)s0*256 + lane*4];
    float4 w1 = *(const float4*)&xw[(size_t)s1*256 + lane*4];
    float4 w2v= *(const float4*)&xw[(size_t)s2*256 + lane*4];
    float4 w3 = *(const float4*)&xw[(size_t)s3*256 + lane*4];
    float a0 = as1[s0*4 + hd];
    float a1 = as1[s1*4 + hd];
    float a2 = as1[s2*4 + hd];
    float a3 = as1[s3*4 + hd];
    float p0 = __expf(leaky(a0 + ad_h) - Mh);
    float p1 = __expf(leaky(a1 + ad_h) - Mh);
    float p2 = __expf(leaky(a2 + ad_h) - Mh);
    float p3 = __expf(leaky(a3 + ad_h) - Mh);
    denom += (p0 + p1) + (p2 + p3);
    acc.x = fmaf(p3, w3.x, fmaf(p2, w2v.x, fmaf(p1, w1.x, fmaf(p0, w0.x, acc.x))));
    acc.y = fmaf(p3, w3.y, fmaf(p2, w2v.y, fmaf(p1, w1.y, fmaf(p0, w0.y, acc.y))));
    acc.z = fmaf(p3, w3.z, fmaf(p2, w2v.z, fmaf(p1, w1.z, fmaf(p0, w0.z, acc.z))));
    acc.w = fmaf(p3, w3.w, fmaf(p2, w2v.w, fmaf(p1, w1.w, fmaf(p0, w0.w, acc.w))));
  }
  for (; i < r1; ++i){
    int s = csr_src[i];
    float4 w = *(const float4*)&xw[(size_t)s*256 + lane*4];
    float a = as1[s*4 + hd];
    float pe = __expf(leaky(a + ad_h) - Mh);
    denom += pe;
    acc.x = fmaf(pe, w.x, acc.x);
    acc.y = fmaf(pe, w.y, acc.y);
    acc.z = fmaf(pe, w.z, acc.z);
    acc.w = fmaf(pe, w.w, acc.w);
  }
  float inv = 1.0f / (denom + 1e-16f);
  float4 bv = *(const float4*)&b1[lane*4];
  float4 o;
  o.x = fmaxf(fmaf(acc.x, inv, bv.x), 0.f);
  o.y = fmaxf(fmaf(acc.y, inv, bv.y), 0.f);
  o.z = fmaxf(fmaf(acc.z, inv, bv.z), 0.f);
  o.w = fmaxf(fmaf(acc.w, inv, bv.w), 0.f);
  // fused layer-2 projection: z[n] = dot(relu(h[n]), w2)
  float4 wv = *(const float4*)&w2[lane*4];
  float d = o.x*wv.x + o.y*wv.y + o.z*wv.z + o.w*wv.w;
  d += __shfl_xor(d, 1);
  d += __shfl_xor(d, 2);
  d += __shfl_xor(d, 4);
  d += __shfl_xor(d, 8);
  d += __shfl_xor(d, 16);
  d += __shfl_xor(d, 32);
  if (lane == 0) z[n] = d;
}

// ---------------- layer-2 aggregation (H=F=1): one wave per node, lanes over edges ----------------
__global__ __launch_bounds__(256) void k_agg2(const int* __restrict__ rowptr, const int* __restrict__ csr_src,
                                              const float* __restrict__ z,
                                              const float* __restrict__ as2p, const float* __restrict__ ad2p,
                                              const float* __restrict__ b2p,
                                              float* __restrict__ out, int N){
  int wave = threadIdx.x >> 6, lane = threadIdx.x & 63;
  int n = blockIdx.x*4 + wave;
  if (n >= N) return;
  float cas = as2p[0], cad = ad2p[0], cb = b2p[0];
  float zn = z[n];
  float adn = cad * zn;
  float e_self = leaky(cas*zn + adn);
  int r0 = __builtin_amdgcn_readfirstlane(rowptr[n]);
  int r1 = __builtin_amdgcn_readfirstlane(rowptr[n+1]);
  float m = e_self;
  for (int i = r0 + lane; i < r1; i += 64){
    int s = csr_src[i];
    m = fmaxf(m, leaky(cas*z[s] + adn));
  }
  m = fmaxf(m, __shfl_xor(m, 1));
  m = fmaxf(m, __shfl_xor(m, 2));
  m = fmaxf(m, __shfl_xor(m, 4));
  m = fmaxf(m, __shfl_xor(m, 8));
  m = fmaxf(m, __shfl_xor(m, 16));
  m = fmaxf(m, __shfl_xor(m, 32));
  float num = 0.f, den = 0.f;
  if (lane == 0){
    float p = __expf(e_self - m);
    den = p; num = p * zn;
  }
  for (int i = r0 + lane; i < r1; i += 64){
    int s = csr_src[i];
    float zs = z[s];
    float e = leaky(cas*zs + adn);
    float p = __expf(e - m);
    den += p;
    num = fmaf(p, zs, num);
  }
  num += __shfl_xor(num, 1);  den += __shfl_xor(den, 1);
  num += __shfl_xor(num, 2);  den += __shfl_xor(den, 2);
  num += __shfl_xor(num, 4);  den += __shfl_xor(den, 4);
  num += __shfl_xor(num, 8);  den += __shfl_xor(den, 8);
  num += __shfl_xor(num, 16); den += __shfl_xor(den, 16);
  num += __shfl_xor(num, 32); den += __shfl_xor(den, 32);
  if (lane == 0) out[n] = num / (den + 1e-16f) + cb;
}

// ---------------- launch ----------------
extern "C" void kernel_launch(void* const* d_in, const int* in_sizes, int n_in,
                              void* d_out, int out_size, void* d_ws, size_t ws_size,
                              hipStream_t stream){
  const float* x    = (const float*)d_in[0];
  const void*  ei   = d_in[1];
  const float* w1   = (const float*)d_in[2];
  const float* asw1 = (const float*)d_in[3];
  const float* adw1 = (const float*)d_in[4];
  const float* b1   = (const float*)d_in[5];
  const float* w2   = (const float*)d_in[6];
  const float* as2  = (const float*)d_in[7];
  const float* ad2  = (const float*)d_in[8];
  const float* b2   = (const float*)d_in[9];
  const int N = in_sizes[0] / 256;
  const int E = in_sizes[1] / 2;
  float* out = (float*)d_out;

  char* wsb = (char*)d_ws;
  size_t off = 0;
  auto alloc = [&](size_t bytes) -> void* {
    void* p = wsb + off;
    off = (off + bytes + 255) & ~(size_t)255;
    return p;
  };
  int*      flag    = (int*)     alloc(4);
  unsigned* gkey    = (unsigned*)alloc(16);
  int*      src     = (int*)     alloc((size_t)E*4);
  int*      dst     = (int*)     alloc((size_t)E*4);
  int*      cnt     = (int*)     alloc((size_t)N*4);
  int*      fill    = (int*)     alloc((size_t)N*4);
  int*      rowptr  = (int*)     alloc((size_t)(N+1)*4);
  int*      bsum    = (int*)     alloc(1024*4);
  int*      csr_src = (int*)     alloc((size_t)E*4);
  float*    xw      = (float*)   alloc((size_t)N*256*4);
  float*    as1     = (float*)   alloc((size_t)N*4*4);
  float*    ad1     = (float*)   alloc((size_t)N*4*4);
  float*    z       = (float*)   alloc((size_t)N*4);

  hipMemsetAsync(gkey, 0, 16, stream);
  hipMemsetAsync(cnt,  0, (size_t)N*4, stream);
  hipMemsetAsync(fill, 0, (size_t)N*4, stream);

  int gE = (E + 255) / 256;
  k_detect     <<<1, 256, 0, stream>>>((const unsigned int*)ei, E, flag);
  k_decode_hist<<<gE, 256, 0, stream>>>(ei, E, flag, src, dst, cnt);
  int nb = (N + 1023) / 1024;
  k_scan1  <<<nb, 256, 0, stream>>>(cnt, rowptr, bsum, N);
  k_scan2  <<<1, 64, 0, stream>>>(bsum, nb);
  k_scan3  <<<nb, 256, 0, stream>>>(rowptr, bsum, N);
  k_scatter<<<gE, 256, 0, stream>>>(src, dst, E, rowptr, fill, csr_src);

  dim3 gG((N + GBM - 1) / GBM, 256 / GBN);
  k_gemm1  <<<gG, 256, 0, stream>>>(x, w1, xw, N);

  int gN4 = (N + 3) / 4;
  k_alphas <<<gN4, 256, 0, stream>>>(xw, asw1, adw1, as1, ad1, N);
  k_maxas  <<<64, 256, 0, stream>>>(as1, gkey, N);
  k_agg1   <<<gN4, 256, 0, stream>>>(rowptr, csr_src, as1, ad1, gkey, xw, b1, w2, z, N);
  k_agg2   <<<gN4, 256, 0, stream>>>(rowptr, csr_src, z, as2, ad2, b2, out, N);
}

// Round 6
// 264.101 us; speedup vs baseline: 1.4907x; 1.4403x over previous
//
#include <hip/hip_runtime.h>
#include <cstdint>
#include <cstddef>

#define NEG_SLOPE 0.2f

typedef _Float16 f16x4 __attribute__((ext_vector_type(4)));
typedef _Float16 f16x8 __attribute__((ext_vector_type(8)));
typedef float    f32x4 __attribute__((ext_vector_type(4)));

static __device__ __forceinline__ float leaky(float x){ return x > 0.f ? x : NEG_SLOPE*x; }
// order-preserving float <-> unsigned key (for atomicMax on floats)
static __device__ __forceinline__ unsigned fkey(float f){
  unsigned u = __float_as_uint(f);
  return (u & 0x80000000u) ? ~u : (u | 0x80000000u);
}
static __device__ __forceinline__ float fdecode(unsigned k){
  return __uint_as_float((k & 0x80000000u) ? (k ^ 0x80000000u) : ~k);
}

// ---------------- edge index dtype detection (sampled, single block) ----------------
__global__ __launch_bounds__(256) void k_detect(const unsigned int* __restrict__ w, int E,
                                                int* __restrict__ flag){
  __shared__ int s;
  if (threadIdx.x == 0) s = 0;
  __syncthreads();
  int nz = 0;
  long long total = 2LL * E;
  #pragma unroll
  for (int j = 0; j < 8; ++j){
    long long idx = ((long long)(threadIdx.x * 8 + j) * total) / 2048;
    idx |= 1;
    if (idx < total) nz |= (w[idx] != 0u);
  }
  if (__any(nz) && (threadIdx.x & 63) == 0) atomicOr(&s, 1);
  __syncthreads();
  if (threadIdx.x == 0) *flag = s;     // 1 => int32, 0 => int64
}

// ---------------- decode + histogram fused ----------------
__global__ __launch_bounds__(256) void k_decode_hist(const void* __restrict__ ei, int E,
                                                     const int* __restrict__ flag,
                                                     int* __restrict__ src, int* __restrict__ dst,
                                                     int* __restrict__ cnt){
  int i = blockIdx.x*256 + threadIdx.x;
  if (i >= E) return;
  int s, d;
  if (*flag){ // int32
    const int* p = (const int*)ei;
    s = p[i]; d = p[E+i];
  } else {    // int64
    const long long* p = (const long long*)ei;
    s = (int)p[i]; d = (int)p[E+i];
  }
  src[i] = s; dst[i] = d;
  atomicAdd(&cnt[d], 1);
}

// ---------------- CSR build by destination ----------------
__global__ __launch_bounds__(256) void k_scan1(const int* __restrict__ cnt, int* __restrict__ rowptr,
                                               int* __restrict__ bsum, int N){
  __shared__ int s[256];
  int tid = threadIdx.x;
  int base = blockIdx.x*1024 + tid*4;
  int v0=0,v1=0,v2=0,v3=0;
  if (base+0 < N) v0 = cnt[base+0];
  if (base+1 < N) v1 = cnt[base+1];
  if (base+2 < N) v2 = cnt[base+2];
  if (base+3 < N) v3 = cnt[base+3];
  s[tid] = v0+v1+v2+v3;
  __syncthreads();
  for (int offd=1; offd<256; offd<<=1){
    int t = (tid>=offd) ? s[tid-offd] : 0;
    __syncthreads();
    s[tid] += t;
    __syncthreads();
  }
  int run = (tid>0) ? s[tid-1] : 0;
  run += v0; if (base+0 < N) rowptr[base+1] = run;
  run += v1; if (base+1 < N) rowptr[base+2] = run;
  run += v2; if (base+2 < N) rowptr[base+3] = run;
  run += v3; if (base+3 < N) rowptr[base+4] = run;
  if (tid==255) bsum[blockIdx.x] = s[255];
}

__global__ void k_scan2(int* __restrict__ bsum, int nb){
  if (threadIdx.x==0 && blockIdx.x==0){
    int acc=0;
    for (int i=0;i<nb;i++){ int t=bsum[i]; bsum[i]=acc; acc+=t; }
  }
}

__global__ __launch_bounds__(256) void k_scan3(int* __restrict__ rowptr, const int* __restrict__ bsum,
                                               int N){
  int tid = threadIdx.x;
  int base = blockIdx.x*1024 + tid*4;
  int add = bsum[blockIdx.x];
  #pragma unroll
  for (int j=0;j<4;j++){ int idx = base+j; if (idx < N) rowptr[idx+1] += add; }
  if (blockIdx.x==0 && tid==0) rowptr[0] = 0;
}

__global__ __launch_bounds__(256) void k_scatter(const int* __restrict__ src, const int* __restrict__ dst,
                                                 int E, const int* __restrict__ rowptr,
                                                 int* __restrict__ fill, int* __restrict__ csr_src){
  int i = blockIdx.x*256 + threadIdx.x;
  if (i >= E) return;
  int d = dst[i];
  int pos = rowptr[d] + atomicAdd(&fill[d], 1);
  csr_src[pos] = src[i];
}

// ---------------- B prep: W[256x256] fp32 -> Bt_hi/Bt_lo[256x256] f16, TRANSPOSED ----------------
__global__ __launch_bounds__(256) void k_prepB(const float* __restrict__ W,
                                               _Float16* __restrict__ Bt_hi, _Float16* __restrict__ Bt_lo){
  int c = blockIdx.x;          // column of W = row of Bt
  int k = threadIdx.x;
  float v = W[k*256 + c];
  _Float16 h = (_Float16)v;
  _Float16 l = (_Float16)(v - (float)h);
  Bt_hi[c*256 + k] = h;
  Bt_lo[c*256 + k] = l;
}

// ---------------- fp16-split MFMA GEMM: xw16[M,256] = f16( A[M,256] @ W[256,256] ) ----------------
// Split A = A_hi + A_lo, W = W_hi + W_lo (f16); acc += Ah*Wh + Ah*Wl + Al*Wh (fp32 MFMA acc).
// Block: 64 rows x full N=256. 4 waves, wave w owns cols [64w, 64w+64).
__global__ __launch_bounds__(256) void k_gemm_f16(const float* __restrict__ A,
                                                  const _Float16* __restrict__ Bt_hi,
                                                  const _Float16* __restrict__ Bt_lo,
                                                  _Float16* __restrict__ xw16, int M){
  __shared__ _Float16 As_hi[64*256];   // 32KB, row stride 512B, XOR-swizzled
  __shared__ _Float16 As_lo[64*256];   // 32KB
  int tid = threadIdx.x;
  int bm = blockIdx.x * 64;

  // ---- stage + convert A tile [64][256] fp32 -> f16 hi/lo in LDS ----
  {
    int r  = tid >> 2;            // 0..63
    int cb = (tid & 3) << 6;      // 0,64,128,192
    bool ok = (bm + r) < M;
    const float* Ar = A + (size_t)(bm + r)*256 + cb;
    char* bh = (char*)As_hi + r*512;
    char* bl = (char*)As_lo + r*512;
    int sw = (r & 7) << 4;
    #pragma unroll
    for (int j = 0; j < 16; ++j){
      float4 v = ok ? *(const float4*)&Ar[j*4] : make_float4(0.f,0.f,0.f,0.f);
      f16x4 h, l;
      h[0]=(_Float16)v.x; l[0]=(_Float16)(v.x-(float)h[0]);
      h[1]=(_Float16)v.y; l[1]=(_Float16)(v.y-(float)h[1]);
      h[2]=(_Float16)v.z; l[2]=(_Float16)(v.z-(float)h[2]);
      h[3]=(_Float16)v.w; l[3]=(_Float16)(v.w-(float)h[3]);
      int boff = ((cb + j*4) << 1) ^ sw;
      *(f16x4*)(bh + boff) = h;
      *(f16x4*)(bl + boff) = l;
    }
  }
  __syncthreads();

  int lane = tid & 63, wv = tid >> 6;
  int frow = lane & 15;      // A-row / B-col within 16-subtile
  int kg   = lane >> 4;      // k-group 0..3

  f32x4 acc[4][4];
  #pragma unroll
  for (int mi=0;mi<4;++mi)
    #pragma unroll
    for (int ni=0;ni<4;++ni) acc[mi][ni] = (f32x4){0.f,0.f,0.f,0.f};

  #pragma unroll
  for (int ks = 0; ks < 8; ++ks){
    f16x8 a_hi[4], a_lo[4];
    #pragma unroll
    for (int mi=0;mi<4;++mi){
      int row = mi*16 + frow;
      int boff = (row*512 + ks*64 + kg*16) ^ ((row & 7) << 4);
      a_hi[mi] = *(const f16x8*)((const char*)As_hi + boff);
      a_lo[mi] = *(const f16x8*)((const char*)As_lo + boff);
    }
    #pragma unroll
    for (int ni=0;ni<4;++ni){
      size_t bofs = (size_t)(wv*64 + ni*16 + frow)*256 + ks*32 + kg*8;
      f16x8 b_hi = *(const f16x8*)(Bt_hi + bofs);
      f16x8 b_lo = *(const f16x8*)(Bt_lo + bofs);
      #pragma unroll
      for (int mi=0;mi<4;++mi){
        acc[mi][ni] = __builtin_amdgcn_mfma_f32_16x16x32_f16(a_hi[mi], b_hi, acc[mi][ni], 0,0,0);
        acc[mi][ni] = __builtin_amdgcn_mfma_f32_16x16x32_f16(a_hi[mi], b_lo, acc[mi][ni], 0,0,0);
        acc[mi][ni] = __builtin_amdgcn_mfma_f32_16x16x32_f16(a_lo[mi], b_hi, acc[mi][ni], 0,0,0);
      }
    }
  }

  // ---- epilogue: D col = lane&15, row = (lane>>4)*4 + reg ----
  #pragma unroll
  for (int mi=0;mi<4;++mi){
    #pragma unroll
    for (int reg=0;reg<4;++reg){
      int row = bm + mi*16 + kg*4 + reg;
      if (row < M){
        #pragma unroll
        for (int ni=0;ni<4;++ni){
          int col = wv*64 + ni*16 + frow;
          xw16[(size_t)row*256 + col] = (_Float16)acc[mi][ni][reg];
        }
      }
    }
  }
}

// ---------------- per-node attention dot products from f16 xw ----------------
__global__ __launch_bounds__(256) void k_alphas(const _Float16* __restrict__ xw16,
                                                const float* __restrict__ a_src, const float* __restrict__ a_dst,
                                                float* __restrict__ as1, float* __restrict__ ad1, int N){
  int wave = threadIdx.x >> 6, lane = threadIdx.x & 63;
  int n = blockIdx.x*4 + wave;
  if (n >= N) return;
  f16x4 v4 = *(const f16x4*)&xw16[(size_t)n*256 + lane*4];
  float4 v = make_float4((float)v4[0], (float)v4[1], (float)v4[2], (float)v4[3]);
  float4 sa = *(const float4*)&a_src[lane*4];
  float4 da = *(const float4*)&a_dst[lane*4];
  float ds = v.x*sa.x + v.y*sa.y + v.z*sa.z + v.w*sa.w;
  float dd = v.x*da.x + v.y*da.y + v.z*da.z + v.w*da.w;
  ds += __shfl_xor(ds, 1);  dd += __shfl_xor(dd, 1);
  ds += __shfl_xor(ds, 2);  dd += __shfl_xor(dd, 2);
  ds += __shfl_xor(ds, 4);  dd += __shfl_xor(dd, 4);
  ds += __shfl_xor(ds, 8);  dd += __shfl_xor(dd, 8);
  if ((lane & 15) == 0){
    int h = lane >> 4;
    as1[n*4 + h] = ds;
    ad1[n*4 + h] = dd;
  }
}

// ---------------- global per-head max of as1 (softmax-stabilization constant) ----------------
__global__ __launch_bounds__(256) void k_maxas(const float* __restrict__ as1, unsigned* __restrict__ gkey,
                                               int N){
  int lane = threadIdx.x & 63;
  float4 m = make_float4(-1e30f,-1e30f,-1e30f,-1e30f);
  for (int n = blockIdx.x*256 + threadIdx.x; n < N; n += gridDim.x*256){
    float4 v = *(const float4*)&as1[(size_t)n*4];
    m.x = fmaxf(m.x, v.x); m.y = fmaxf(m.y, v.y);
    m.z = fmaxf(m.z, v.z); m.w = fmaxf(m.w, v.w);
  }
  #pragma unroll
  for (int off = 1; off < 64; off <<= 1){
    m.x = fmaxf(m.x, __shfl_xor(m.x, off));
    m.y = fmaxf(m.y, __shfl_xor(m.y, off));
    m.z = fmaxf(m.z, __shfl_xor(m.z, off));
    m.w = fmaxf(m.w, __shfl_xor(m.w, off));
  }
  if (lane == 0){
    atomicMax(&gkey[0], fkey(m.x));
    atomicMax(&gkey[1], fkey(m.y));
    atomicMax(&gkey[2], fkey(m.z));
    atomicMax(&gkey[3], fkey(m.w));
  }
}

// ---------------- layer-1 aggregation (f16 gathers) + fused layer-2 projection ----------------
__global__ __launch_bounds__(256) void k_agg1(const int* __restrict__ rowptr, const int* __restrict__ csr_src,
                                              const float* __restrict__ as1, const float* __restrict__ ad1,
                                              const unsigned* __restrict__ gkey,
                                              const _Float16* __restrict__ xw16, const float* __restrict__ b1,
                                              const float* __restrict__ w2,
                                              float* __restrict__ z, int N){
  int wave = threadIdx.x >> 6, lane = threadIdx.x & 63;
  int n = blockIdx.x*4 + wave;
  if (n >= N) return;
  int hd = lane >> 4;
  float ad_h  = ad1[n*4 + hd];
  float as_n  = as1[n*4 + hd];
  float Mh = leaky(fdecode(gkey[hd]) + ad_h);
  float p = __expf(leaky(as_n + ad_h) - Mh);   // self loop
  float denom = p;
  f16x4 sv = *(const f16x4*)&xw16[(size_t)n*256 + lane*4];
  float4 acc;
  acc.x = p*(float)sv[0]; acc.y = p*(float)sv[1]; acc.z = p*(float)sv[2]; acc.w = p*(float)sv[3];
  int r0 = __builtin_amdgcn_readfirstlane(rowptr[n]);
  int r1 = __builtin_amdgcn_readfirstlane(rowptr[n+1]);
  int i = r0;
  for (; i + 4 <= r1; i += 4){
    int s0 = csr_src[i], s1 = csr_src[i+1], s2 = csr_src[i+2], s3 = csr_src[i+3];
    f16x4 w0 = *(const f16x4*)&xw16[(size_t)s0*256 + lane*4];
    f16x4 w1 = *(const f16x4*)&xw16[(size_t)s1*256 + lane*4];
    f16x4 w2v= *(const f16x4*)&xw16[(size_t)s2*256 + lane*4];
    f16x4 w3 = *(const f16x4*)&xw16[(size_t)s3*256 + lane*4];
    float a0 = as1[s0*4 + hd];
    float a1 = as1[s1*4 + hd];
    float a2 = as1[s2*4 + hd];
    float a3 = as1[s3*4 + hd];
    float p0 = __expf(leaky(a0 + ad_h) - Mh);
    float p1 = __expf(leaky(a1 + ad_h) - Mh);
    float p2 = __expf(leaky(a2 + ad_h) - Mh);
    float p3 = __expf(leaky(a3 + ad_h) - Mh);
    denom += (p0 + p1) + (p2 + p3);
    acc.x = fmaf(p3,(float)w3[0], fmaf(p2,(float)w2v[0], fmaf(p1,(float)w1[0], fmaf(p0,(float)w0[0], acc.x))));
    acc.y = fmaf(p3,(float)w3[1], fmaf(p2,(float)w2v[1], fmaf(p1,(float)w1[1], fmaf(p0,(float)w0[1], acc.y))));
    acc.z = fmaf(p3,(float)w3[2], fmaf(p2,(float)w2v[2], fmaf(p1,(float)w1[2], fmaf(p0,(float)w0[2], acc.z))));
    acc.w = fmaf(p3,(float)w3[3], fmaf(p2,(float)w2v[3], fmaf(p1,(float)w1[3], fmaf(p0,(float)w0[3], acc.w))));
  }
  for (; i < r1; ++i){
    int s = csr_src[i];
    f16x4 w = *(const f16x4*)&xw16[(size_t)s*256 + lane*4];
    float a = as1[s*4 + hd];
    float pe = __expf(leaky(a + ad_h) - Mh);
    denom += pe;
    acc.x = fmaf(pe,(float)w[0], acc.x);
    acc.y = fmaf(pe,(float)w[1], acc.y);
    acc.z = fmaf(pe,(float)w[2], acc.z);
    acc.w = fmaf(pe,(float)w[3], acc.w);
  }
  float inv = 1.0f / (denom + 1e-16f);
  float4 bv = *(const float4*)&b1[lane*4];
  float4 o;
  o.x = fmaxf(fmaf(acc.x, inv, bv.x), 0.f);
  o.y = fmaxf(fmaf(acc.y, inv, bv.y), 0.f);
  o.z = fmaxf(fmaf(acc.z, inv, bv.z), 0.f);
  o.w = fmaxf(fmaf(acc.w, inv, bv.w), 0.f);
  // fused layer-2 projection: z[n] = dot(relu(h[n]), w2)
  float4 wv = *(const float4*)&w2[lane*4];
  float d = o.x*wv.x + o.y*wv.y + o.z*wv.z + o.w*wv.w;
  d += __shfl_xor(d, 1);
  d += __shfl_xor(d, 2);
  d += __shfl_xor(d, 4);
  d += __shfl_xor(d, 8);
  d += __shfl_xor(d, 16);
  d += __shfl_xor(d, 32);
  if (lane == 0) z[n] = d;
}

// ---------------- layer-2 aggregation (H=F=1) ----------------
__global__ __launch_bounds__(256) void k_agg2(const int* __restrict__ rowptr, const int* __restrict__ csr_src,
                                              const float* __restrict__ z,
                                              const float* __restrict__ as2p, const float* __restrict__ ad2p,
                                              const float* __restrict__ b2p,
                                              float* __restrict__ out, int N){
  int wave = threadIdx.x >> 6, lane = threadIdx.x & 63;
  int n = blockIdx.x*4 + wave;
  if (n >= N) return;
  float cas = as2p[0], cad = ad2p[0], cb = b2p[0];
  float zn = z[n];
  float adn = cad * zn;
  float e_self = leaky(cas*zn + adn);
  int r0 = __builtin_amdgcn_readfirstlane(rowptr[n]);
  int r1 = __builtin_amdgcn_readfirstlane(rowptr[n+1]);
  float m = e_self;
  for (int i = r0 + lane; i < r1; i += 64){
    int s = csr_src[i];
    m = fmaxf(m, leaky(cas*z[s] + adn));
  }
  m = fmaxf(m, __shfl_xor(m, 1));
  m = fmaxf(m, __shfl_xor(m, 2));
  m = fmaxf(m, __shfl_xor(m, 4));
  m = fmaxf(m, __shfl_xor(m, 8));
  m = fmaxf(m, __shfl_xor(m, 16));
  m = fmaxf(m, __shfl_xor(m, 32));
  float num = 0.f, den = 0.f;
  if (lane == 0){
    float p = __expf(e_self - m);
    den = p; num = p * zn;
  }
  for (int i = r0 + lane; i < r1; i += 64){
    int s = csr_src[i];
    float zs = z[s];
    float e = leaky(cas*zs + adn);
    float p = __expf(e - m);
    den += p;
    num = fmaf(p, zs, num);
  }
  num += __shfl_xor(num, 1);  den += __shfl_xor(den, 1);
  num += __shfl_xor(num, 2);  den += __shfl_xor(den, 2);
  num += __shfl_xor(num, 4);  den += __shfl_xor(den, 4);
  num += __shfl_xor(num, 8);  den += __shfl_xor(den, 8);
  num += __shfl_xor(num, 16); den += __shfl_xor(den, 16);
  num += __shfl_xor(num, 32); den += __shfl_xor(den, 32);
  if (lane == 0) out[n] = num / (den + 1e-16f) + cb;
}

// ---------------- launch ----------------
extern "C" void kernel_launch(void* const* d_in, const int* in_sizes, int n_in,
                              void* d_out, int out_size, void* d_ws, size_t ws_size,
                              hipStream_t stream){
  const float* x    = (const float*)d_in[0];
  const void*  ei   = d_in[1];
  const float* w1   = (const float*)d_in[2];
  const float* asw1 = (const float*)d_in[3];
  const float* adw1 = (const float*)d_in[4];
  const float* b1   = (const float*)d_in[5];
  const float* w2   = (const float*)d_in[6];
  const float* as2  = (const float*)d_in[7];
  const float* ad2  = (const float*)d_in[8];
  const float* b2   = (const float*)d_in[9];
  const int N = in_sizes[0] / 256;
  const int E = in_sizes[1] / 2;
  float* out = (float*)d_out;

  char* wsb = (char*)d_ws;
  size_t off = 0;
  auto alloc = [&](size_t bytes) -> void* {
    void* p = wsb + off;
    off = (off + bytes + 255) & ~(size_t)255;
    return p;
  };
  int*       flag    = (int*)      alloc(4);
  unsigned*  gkey    = (unsigned*) alloc(16);
  int*       src     = (int*)      alloc((size_t)E*4);
  int*       dst     = (int*)      alloc((size_t)E*4);
  int*       cnt     = (int*)      alloc((size_t)N*4);
  int*       fill    = (int*)      alloc((size_t)N*4);
  int*       rowptr  = (int*)      alloc((size_t)(N+1)*4);
  int*       bsum    = (int*)      alloc(1024*4);
  int*       csr_src = (int*)      alloc((size_t)E*4);
  _Float16*  Bt_hi   = (_Float16*) alloc((size_t)256*256*2);
  _Float16*  Bt_lo   = (_Float16*) alloc((size_t)256*256*2);
  _Float16*  xw16    = (_Float16*) alloc((size_t)N*256*2);
  float*     as1     = (float*)    alloc((size_t)N*4*4);
  float*     ad1     = (float*)    alloc((size_t)N*4*4);
  float*     z       = (float*)    alloc((size_t)N*4);

  hipMemsetAsync(gkey, 0, 16, stream);
  hipMemsetAsync(cnt,  0, (size_t)N*4, stream);
  hipMemsetAsync(fill, 0, (size_t)N*4, stream);

  int gE = (E + 255) / 256;
  k_detect     <<<1, 256, 0, stream>>>((const unsigned int*)ei, E, flag);
  k_decode_hist<<<gE, 256, 0, stream>>>(ei, E, flag, src, dst, cnt);
  int nb = (N + 1023) / 1024;
  k_scan1  <<<nb, 256, 0, stream>>>(cnt, rowptr, bsum, N);
  k_scan2  <<<1, 64, 0, stream>>>(bsum, nb);
  k_scan3  <<<nb, 256, 0, stream>>>(rowptr, bsum, N);
  k_scatter<<<gE, 256, 0, stream>>>(src, dst, E, rowptr, fill, csr_src);

  k_prepB   <<<256, 256, 0, stream>>>(w1, Bt_hi, Bt_lo);
  k_gemm_f16<<<(N + 63) / 64, 256, 0, stream>>>(x, Bt_hi, Bt_lo, xw16, N);

  int gN4 = (N + 3) / 4;
  k_alphas <<<gN4, 256, 0, stream>>>(xw16, asw1, adw1, as1, ad1, N);
  k_maxas  <<<64, 256, 0, stream>>>(as1, gkey, N);
  k_agg1   <<<gN4, 256, 0, stream>>>(rowptr, csr_src, as1, ad1, gkey, xw16, b1, w2, z, N);
  k_agg2   <<<gN4, 256, 0, stream>>>(rowptr, csr_src, z, as2, ad2, b2, out, N);
}